// Round 2
// baseline (1412.418 us; speedup 1.0000x reference)
//
#include <hip/hip_runtime.h>
#include <cstdint>
#include <cstddef>

// ---------------------------------------------------------------------------
// Types / helpers
// ---------------------------------------------------------------------------
using bf16x8 = __attribute__((ext_vector_type(8))) __bf16;
using f32x4  = __attribute__((ext_vector_type(4))) float;

__device__ __forceinline__ unsigned short f2bf(float f) {
  union { float f; uint32_t u; } v; v.f = f;
  uint32_t r = (v.u + 0x7fffu + ((v.u >> 16) & 1u)) >> 16;
  return (unsigned short)r;
}

__device__ __forceinline__ float waveRed(float v) {
#pragma unroll
  for (int m = 32; m >= 1; m >>= 1) v += __shfl_xor(v, m, 64);
  return v;
}

// async global->LDS, 16B per lane. LDS dest must be wave-uniform base + lane*16.
__device__ __forceinline__ void gload16(const void* g, void* l) {
  __builtin_amdgcn_global_load_lds(
      (__attribute__((address_space(1))) uint32_t*)(uintptr_t)g,
      (__attribute__((address_space(3))) uint32_t*)(uint32_t*)l,
      16, 0, 0);
}

// ---------------------------------------------------------------------------
// Small utility kernels
// ---------------------------------------------------------------------------
__global__ void zero_k(float* __restrict__ p, int n) {
  for (int i = blockIdx.x * 256 + threadIdx.x; i < n; i += gridDim.x * 256) p[i] = 0.f;
}

__global__ void cvtx_k(const float4* __restrict__ x, ushort4* __restrict__ xb,
                       float* __restrict__ sumsq, int n4) {
  float s = 0.f;
  for (int i = blockIdx.x * 256 + threadIdx.x; i < n4; i += gridDim.x * 256) {
    float4 v = x[i];
    ushort4 o;
    o.x = f2bf(v.x); o.y = f2bf(v.y); o.z = f2bf(v.z); o.w = f2bf(v.w);
    xb[i] = o;
    s += v.x * v.x + v.y * v.y + v.z * v.z + v.w * v.w;
  }
  s = waveRed(s);
  if ((threadIdx.x & 63) == 0) atomicAdd(sumsq, s);
}

__global__ void cvtw_k(const float4* __restrict__ in, ushort4* __restrict__ out, int n4) {
  for (int i = blockIdx.x * 256 + threadIdx.x; i < n4; i += gridDim.x * 256) {
    float4 v = in[i];
    ushort4 o;
    o.x = f2bf(v.x); o.y = f2bf(v.y); o.z = f2bf(v.z); o.w = f2bf(v.w);
    out[i] = o;
  }
}

// out[c*R + r] = f2bf(in[r*C + c]);  in: R x C fp32, out: C x R bf16
__global__ void trf_k(const float* __restrict__ in, unsigned short* __restrict__ out,
                      int R, int C, int n) {
  for (int o = blockIdx.x * 256 + threadIdx.x; o < n; o += gridDim.x * 256) {
    int c = o / R, r = o - c * R;
    out[o] = f2bf(in[(size_t)r * C + c]);
  }
}

// bf16 transpose: out[c*R + r] = in[r*C + c]
__global__ void trb_k(const unsigned short* __restrict__ in, unsigned short* __restrict__ out,
                      int R, int C, int n) {
  for (int o = blockIdx.x * 256 + threadIdx.x; o < n; o += gridDim.x * 256) {
    int c = o / R, r = o - c * R;
    out[o] = in[(size_t)r * C + c];
  }
}

// LDS-histogram count: 32 blocks -> <=16K contended global atomics (was 65K)
__global__ __launch_bounds__(256) void count_k(const int* __restrict__ lab,
                                               int* __restrict__ counts, int n) {
  __shared__ int h[512];
  for (int i = threadIdx.x; i < 512; i += 256) h[i] = 0;
  __syncthreads();
  for (int i = blockIdx.x * 256 + threadIdx.x; i < n; i += gridDim.x * 256)
    atomicAdd(&h[lab[i]], 1);
  __syncthreads();
  for (int i = threadIdx.x; i < 512; i += 256) {
    int v = h[i];
    if (v) atomicAdd(&counts[i], v);
  }
}

// single-wave shuffle scan (replaces serial single-thread prefix: ~512 dependent
// global round-trips -> 8 shuffle-scan rounds)
__global__ void prefix_k(const int* __restrict__ counts, int* __restrict__ offsets,
                         int* __restrict__ cursor, int nc) {
  const int lane = threadIdx.x;  // 64 threads
  int base = 0;
  for (int c0 = 0; c0 < nc; c0 += 64) {
    int v = counts[c0 + lane];
    int x = v;
#pragma unroll
    for (int d = 1; d < 64; d <<= 1) {
      int y = __shfl_up(x, d, 64);
      if (lane >= d) x += y;
    }
    int excl = base + x - v;
    offsets[c0 + lane] = excl;
    cursor[c0 + lane] = excl;
    base += __shfl(x, 63, 64);
  }
}

__global__ void scatter_k(const int* __restrict__ lab, int* __restrict__ cursor,
                          int* __restrict__ buckets, int n) {
  for (int i = blockIdx.x * 256 + threadIdx.x; i < n; i += gridDim.x * 256) {
    int pos = atomicAdd(&cursor[lab[i]], 1);
    buckets[pos] = i;
  }
}

// one block per class: sum rows (bucket list cached in LDS, 4x unrolled),
// then atomicAdd(||sums||^2 / count)
__global__ __launch_bounds__(256) void center_k(const float* __restrict__ x,
    const int* __restrict__ buckets, const int* __restrict__ offsets,
    const int* __restrict__ counts, float* __restrict__ out, int D) {
  const int c = blockIdx.x;
  const int cnt = counts[c];
  if (cnt == 0) return;
  const int beg = offsets[c];
  __shared__ int rs[512];
  const int d2 = threadIdx.x;            // D/2 == 256 threads
  float sx = 0.f, sy = 0.f;
  for (int base = 0; base < cnt; base += 512) {
    const int m = min(cnt - base, 512);
    __syncthreads();
    for (int i = threadIdx.x; i < m; i += 256) rs[i] = buckets[beg + base + i];
    __syncthreads();
    int r = 0;
    for (; r + 4 <= m; r += 4) {
      const float2 v0 = ((const float2*)(x + (size_t)rs[r + 0] * D))[d2];
      const float2 v1 = ((const float2*)(x + (size_t)rs[r + 1] * D))[d2];
      const float2 v2 = ((const float2*)(x + (size_t)rs[r + 2] * D))[d2];
      const float2 v3 = ((const float2*)(x + (size_t)rs[r + 3] * D))[d2];
      sx += v0.x + v1.x + v2.x + v3.x;
      sy += v0.y + v1.y + v2.y + v3.y;
    }
    for (; r < m; ++r) {
      const float2 v = ((const float2*)(x + (size_t)rs[r] * D))[d2];
      sx += v.x; sy += v.y;
    }
  }
  float ssq = sx * sx + sy * sy;
  ssq = waveRed(ssq);
  __shared__ float red[4];
  if ((threadIdx.x & 63) == 0) red[threadIdx.x >> 6] = ssq;
  __syncthreads();
  if (threadIdx.x == 0)
    atomicAdd(out, (red[0] + red[1] + red[2] + red[3]) / (float)cnt);
}

__global__ void copy_k(const float* __restrict__ in, float* __restrict__ out, int n) {
  for (int i = blockIdx.x * 256 + threadIdx.x; i < n; i += gridDim.x * 256) out[i] = in[i];
}

// vout[row] = badd[row] + sum_k W[row,K] vin[k]; one block per row
__global__ __launch_bounds__(256) void matvec_k(const float* __restrict__ W,
    const float* __restrict__ vin, const float* __restrict__ badd,
    float* __restrict__ vout, int K) {
  int row = blockIdx.x;
  float s = 0.f;
  for (int k = threadIdx.x; k < K; k += 256) s += W[(size_t)row * K + k] * vin[k];
  s = waveRed(s);
  __shared__ float red[4];
  if ((threadIdx.x & 63) == 0) red[threadIdx.x >> 6] = s;
  __syncthreads();
  if (threadIdx.x == 0) vout[row] = red[0] + red[1] + red[2] + red[3] + badd[row];
}

// ---------------------------------------------------------------------------
// bf16 MFMA GEMM (m97 structure), used only for the small weight-collapse
// products: C[M,N] = A[M,K] @ B[N,K]^T, bf16 out.
// ---------------------------------------------------------------------------
#define BM 128
#define BN 128
#define BKK 32

__global__ __launch_bounds__(256) void gemm_bt(
    const unsigned short* __restrict__ A, const unsigned short* __restrict__ Bm,
    int M, int N, int K, unsigned short* __restrict__ Cout) {
  __shared__ __align__(16) unsigned short As[BM * BKK];
  __shared__ __align__(16) unsigned short Bs[BN * BKK];
  const int tid = threadIdx.x;
  const int lane = tid & 63;
  const int wave = tid >> 6;
  const int lane16 = lane & 15;
  const int quad = lane >> 4;
  const int wm = (wave >> 1) * 64;
  const int wn = (wave & 1) * 64;
  const int m0 = blockIdx.y * BM;
  const int n0 = blockIdx.x * BN;

  f32x4 acc[4][4] = {};

  const int srow = tid >> 2;
  const int skof = (tid & 3) * 8;
  const unsigned short* Ab = A + (size_t)(m0 + srow) * K + skof;
  const unsigned short* Bb = Bm + (size_t)(n0 + srow) * K + skof;
  const size_t rstep = (size_t)64 * K;

  for (int kt = 0; kt < K; kt += BKK) {
    gload16(Ab + kt,         &As[tid * 8]);
    gload16(Ab + rstep + kt, &As[2048 + tid * 8]);
    gload16(Bb + kt,         &Bs[tid * 8]);
    gload16(Bb + rstep + kt, &Bs[2048 + tid * 8]);
    __syncthreads();
    bf16x8 af[4], bfv[4];
#pragma unroll
    for (int i = 0; i < 4; ++i)
      af[i] = *(const bf16x8*)&As[(wm + i * 16 + lane16) * BKK + quad * 8];
#pragma unroll
    for (int j = 0; j < 4; ++j)
      bfv[j] = *(const bf16x8*)&Bs[(wn + j * 16 + lane16) * BKK + quad * 8];
#pragma unroll
    for (int i = 0; i < 4; ++i)
#pragma unroll
      for (int j = 0; j < 4; ++j)
        acc[i][j] = __builtin_amdgcn_mfma_f32_16x16x32_bf16(af[i], bfv[j], acc[i][j], 0, 0, 0);
    __syncthreads();
  }
#pragma unroll
  for (int i = 0; i < 4; ++i)
#pragma unroll
    for (int r = 0; r < 4; ++r) {
      const int rowg = m0 + wm + i * 16 + quad * 4 + r;
#pragma unroll
      for (int j = 0; j < 4; ++j) {
        const int colg = n0 + wn + j * 16 + lane16;
        Cout[(size_t)rowg * N + colg] = f2bf(acc[i][j][r]);
      }
    }
}

// ---------------------------------------------------------------------------
// Persistent-A fused logits+CE GEMM.
// Block = 64 rows of x, A stripe (64x512 bf16 = 64KB) staged ONCE in LDS with
// XOR-chunk swizzle (conflict-free ds_read_b128). No barriers in the panel
// loop. B fragments loaded global->VGPR (B = 3.67MB, L2-resident per XCD)
// with depth-1 prefetch + immediate offsets. 4 waves x (64 rows x 64 cols)
// per 256-col panel-pair; K=512 fully accumulated per pair (16 ksteps x 16
// MFMA). exp-sums / picked-logit / labels live in registers across all
// panels; one cross-wave LDS reduction at the end reuses the dead A tile.
// ---------------------------------------------------------------------------
template <int NPAIR>
__device__ __forceinline__ void ce_pairs(
    const unsigned short* __restrict__ Bm, const float* __restrict__ bias,
    const unsigned short* As, const int cbase,
    const int wave, const int lane16, const int quad, const int (&labr)[16],
    float (&es)[16], float& pk) {
#pragma unroll 1
  for (int p = 0; p < NPAIR; ++p) {
    const int c0 = cbase + p * 256 + wave * 64;          // wave's first col
    const unsigned short* bp = Bm + (size_t)(c0 + lane16) * 512 + quad * 8;
    f32x4 acc[4][4] = {};
    bf16x8 bcur[4], bnxt[4];
#pragma unroll
    for (int j = 0; j < 4; ++j) bcur[j] = *(const bf16x8*)(bp + j * (16 * 512));
#pragma unroll
    for (int t = 0; t < 16; ++t) {
      if (t < 15) {
#pragma unroll
        for (int j = 0; j < 4; ++j)
          bnxt[j] = *(const bf16x8*)(bp + j * (16 * 512) + (t + 1) * 32);
      }
      bf16x8 af[4];
#pragma unroll
      for (int i = 0; i < 4; ++i) {
        const int arow = i * 16 + lane16;
        const int ch = (t * 4 + quad) ^ (arow & 7);      // un-swizzle
        af[i] = *(const bf16x8*)&As[arow * 512 + ch * 8];
      }
#pragma unroll
      for (int i = 0; i < 4; ++i)
#pragma unroll
        for (int j = 0; j < 4; ++j)
          acc[i][j] = __builtin_amdgcn_mfma_f32_16x16x32_bf16(af[i], bcur[j], acc[i][j], 0, 0, 0);
      if (t < 15) {
#pragma unroll
        for (int j = 0; j < 4; ++j) bcur[j] = bnxt[j];
      }
    }
    // epilogue: fold logits into register CE accumulators
    float bj[4];
    int colr[4];
#pragma unroll
    for (int j = 0; j < 4; ++j) {
      bj[j] = bias[c0 + j * 16 + lane16];
      colr[j] = c0 + j * 16 + lane16 - cbase;
    }
#pragma unroll
    for (int i = 0; i < 4; ++i)
#pragma unroll
      for (int r = 0; r < 4; ++r) {
        const int lb = labr[i * 4 + r];
        float e = 0.f;
#pragma unroll
        for (int j = 0; j < 4; ++j) {
          const float v = acc[i][j][r] + bj[j];
          e += __expf(v);
          if (colr[j] == lb) pk += v;
        }
        es[i * 4 + r] += e;
      }
  }
}

__global__ __launch_bounds__(256, 2) void gemm_ce(
    const unsigned short* __restrict__ A,   // Bsz x 512 bf16 (x)
    const unsigned short* __restrict__ Bm,  // 3584 x 512 bf16 (Bcat)
    const float* __restrict__ bias,         // 3584 fp32
    const int* __restrict__ labels,
    float* __restrict__ nll_acc) {          // 3 floats: sum(log es) - sum(picked)
  __shared__ __align__(16) unsigned short As[64 * 512];  // exactly 64 KB
  const int tid = threadIdx.x;
  const int lane = tid & 63;
  const int wave = tid >> 6;
  const int lane16 = lane & 15;
  const int quad = lane >> 4;
  const int m0 = blockIdx.x * 64;

  // stage A (64 rows x 512) once, chunk-XOR swizzled: LDS[row][c] = glb chunk c^(row&7)
#pragma unroll
  for (int s = 0; s < 16; ++s) {
    const int row = s * 4 + wave;
    const int gch = lane ^ (row & 7);
    gload16(A + (size_t)(m0 + row) * 512 + gch * 8, &As[(row * 64 + lane) * 8]);
  }
  int labr[16];
#pragma unroll
  for (int i = 0; i < 4; ++i)
#pragma unroll
    for (int r = 0; r < 4; ++r)
      labr[i * 4 + r] = labels[m0 + i * 16 + quad * 4 + r];
  __syncthreads();

  float es0[16] = {}, es1[16] = {}, es2[16] = {};
  float pk0 = 0.f, pk1 = 0.f, pk2 = 0.f;

  ce_pairs<8>(Bm, bias, As, 0,    wave, lane16, quad, labr, es0, pk0);  // level0: cols 0..2047
  ce_pairs<4>(Bm, bias, As, 2048, wave, lane16, quad, labr, es1, pk1);  // level1: 2048..3071
  ce_pairs<2>(Bm, bias, As, 3072, wave, lane16, quad, labr, es2, pk2);  // level2: 3072..3583

  // ---- cross-wave reduction; A tile is dead, reuse as float scratch ----
  __syncthreads();
  float* sh = (float*)As;   // [0..63]=es L0, [64..127]=L1, [128..191]=L2, [192..194]=log-sums
  if (tid < 195) sh[tid] = 0.f;

  pk0 = waveRed(pk0); pk1 = waveRed(pk1); pk2 = waveRed(pk2);
  if (lane == 0) {
    atomicAdd(&nll_acc[0], -pk0);
    atomicAdd(&nll_acc[1], -pk1);
    atomicAdd(&nll_acc[2], -pk2);
  }
  __syncthreads();
#pragma unroll
  for (int k = 0; k < 16; ++k) {
    float v0 = es0[k], v1 = es1[k], v2 = es2[k];
#pragma unroll
    for (int m = 1; m <= 8; m <<= 1) {
      v0 += __shfl_xor(v0, m, 64);
      v1 += __shfl_xor(v1, m, 64);
      v2 += __shfl_xor(v2, m, 64);
    }
    if (lane16 == 0) {
      const int row = (k >> 2) * 16 + quad * 4 + (k & 3);
      atomicAdd(&sh[row], v0);
      atomicAdd(&sh[64 + row], v1);
      atomicAdd(&sh[128 + row], v2);
    }
  }
  __syncthreads();
  if (tid < 192) {
    const float v = __logf(sh[tid]);
    atomicAdd(&sh[192 + (tid >> 6)], v);
  }
  __syncthreads();
  if (tid < 3) atomicAdd(&nll_acc[tid], sh[192 + tid]);
}

// scal: [0]=sumsq_x [1]=sum ||sums_c||^2/n_c  [2..4]=nll sums
__global__ void fin_k(const float* __restrict__ scal, const float* __restrict__ lam,
                      float* __restrict__ out, float invB) {
  if (threadIdx.x == 0 && blockIdx.x == 0)
    out[0] = lam[0] * (scal[0] - scal[1]) +
             (lam[1] * scal[2] + lam[2] * scal[3] + lam[3] * scal[4]) * invB;
}

// ---------------------------------------------------------------------------
// Launch
// ---------------------------------------------------------------------------
extern "C" void kernel_launch(void* const* d_in, const int* in_sizes, int n_in,
                              void* d_out, int out_size, void* d_ws, size_t ws_size,
                              hipStream_t stream) {
  const float* x   = (const float*)d_in[0];
  const float* W0  = (const float*)d_in[1];
  const float* b0  = (const float*)d_in[2];
  const float* W1  = (const float*)d_in[3];
  const float* b1  = (const float*)d_in[4];
  const float* W2  = (const float*)d_in[5];
  const float* b2  = (const float*)d_in[6];
  const float* lam = (const float*)d_in[7];
  const int*   lab = (const int*)d_in[8];

  const int Bsz = in_sizes[8];         // 65536
  const int D   = in_sizes[0] / Bsz;   // 512
  const int N0  = in_sizes[2];         // 2048
  const int N1  = in_sizes[4];         // 1024
  const int N2  = in_sizes[6];         // 512
  const int Ncat = N0 + N1 + N2;       // 3584
  const int NCLS = 512;

  char* w = (char*)d_ws;
  size_t off = 0;
  auto alloc = [&](size_t bytes) -> void* {
    void* p = w + off;
    off += (bytes + 255) & ~(size_t)255;
    return p;
  };

  unsigned short* xb   = (unsigned short*)alloc((size_t)Bsz * D * 2);
  unsigned short* Bcat = (unsigned short*)alloc((size_t)Ncat * D * 2);
  unsigned short* W0b  = Bcat;
  unsigned short* M1   = Bcat + (size_t)N0 * D;
  unsigned short* M2   = Bcat + (size_t)(N0 + N1) * D;
  unsigned short* W0t  = (unsigned short*)alloc((size_t)D * N0 * 2);
  unsigned short* W1b  = (unsigned short*)alloc((size_t)N1 * N0 * 2);
  unsigned short* W2b  = (unsigned short*)alloc((size_t)N2 * N1 * 2);
  unsigned short* M1t  = (unsigned short*)alloc((size_t)D * N1 * 2);
  float* biascat = (float*)alloc((size_t)Ncat * 4);
  int* offsets = (int*)alloc(NCLS * 4);
  int* cursor  = (int*)alloc(NCLS * 4);
  int* buckets = (int*)alloc((size_t)Bsz * 4);
  // zero region: counts(512 int) | scal(8 float)
  size_t zbytes = (size_t)NCLS * 4 + 32;
  char* zr = (char*)alloc(zbytes);
  int*   counts = (int*)zr;
  float* scal   = (float*)(zr + NCLS * 4);
  (void)ws_size; (void)n_in; (void)out_size;

  const int zwords = (int)(zbytes / 4);
  zero_k<<<dim3(3), dim3(256), 0, stream>>>((float*)zr, zwords);

  // x -> bf16 + sum of squares
  const int n4x = Bsz * D / 4;
  cvtx_k<<<dim3(1024), dim3(256), 0, stream>>>((const float4*)x, (ushort4*)xb, &scal[0], n4x);

  // weight conversions
  cvtw_k<<<dim3((N0 * D / 4 + 255) / 256), dim3(256), 0, stream>>>((const float4*)W0, (ushort4*)W0b, N0 * D / 4);
  cvtw_k<<<dim3((N1 * N0 / 4 + 255) / 256), dim3(256), 0, stream>>>((const float4*)W1, (ushort4*)W1b, N1 * N0 / 4);
  cvtw_k<<<dim3((N2 * N1 / 4 + 255) / 256), dim3(256), 0, stream>>>((const float4*)W2, (ushort4*)W2b, N2 * N1 / 4);
  trf_k<<<dim3(4096), dim3(256), 0, stream>>>(W0, W0t, N0, D, N0 * D);

  // center-loss bucketing
  count_k<<<dim3(32), dim3(256), 0, stream>>>(lab, counts, Bsz);
  prefix_k<<<dim3(1), dim3(64), 0, stream>>>(counts, offsets, cursor, NCLS);
  scatter_k<<<dim3(256), dim3(256), 0, stream>>>(lab, cursor, buckets, Bsz);
  center_k<<<dim3(NCLS), dim3(256), 0, stream>>>(x, buckets, offsets, counts, &scal[1], D);

  // collapsed biases: biascat = [b0 | b1 + W1 b0 | b2 + W2 c1]
  copy_k<<<dim3(8), dim3(256), 0, stream>>>(b0, biascat, N0);
  matvec_k<<<dim3(N1), dim3(256), 0, stream>>>(W1, b0, b1, biascat + N0, N0);
  matvec_k<<<dim3(N2), dim3(256), 0, stream>>>(W2, biascat + N0, b2, biascat + N0 + N1, N1);

  // collapsed weights: M1 = W1@W0 (N1 x D), M2 = W2@M1 (N2 x D)
  gemm_bt<<<dim3(D / BN, N1 / BM), dim3(256), 0, stream>>>(W1b, W0t, N1, D, N0, M1);
  trb_k<<<dim3(2048), dim3(256), 0, stream>>>(M1, M1t, N1, D, N1 * D);
  gemm_bt<<<dim3(D / BN, N2 / BM), dim3(256), 0, stream>>>(W2b, M1t, N2, D, N1, M2);

  // fused logits + CE, all three levels
  gemm_ce<<<dim3(Bsz / 64), dim3(256), 0, stream>>>(xb, Bcat, biascat, lab, &scal[2]);

  fin_k<<<dim3(1), dim3(64), 0, stream>>>(scal, lam, (float*)d_out, 1.f / (float)Bsz);
}

// Round 3
// 763.694 us; speedup vs baseline: 1.8495x; 1.8495x over previous
//
#include <hip/hip_runtime.h>
#include <cstdint>
#include <cstddef>

// ---------------------------------------------------------------------------
// Types / helpers
// ---------------------------------------------------------------------------
using bf16x8 = __attribute__((ext_vector_type(8))) __bf16;
using f32x4  = __attribute__((ext_vector_type(4))) float;
using i32x4v = __attribute__((ext_vector_type(4))) int;
using i32x8v = __attribute__((ext_vector_type(8))) int;

__device__ __forceinline__ unsigned short f2bf(float f) {
  union { float f; uint32_t u; } v; v.f = f;
  uint32_t r = (v.u + 0x7fffu + ((v.u >> 16) & 1u)) >> 16;
  return (unsigned short)r;
}

__device__ __forceinline__ unsigned char f2fp8(float f) {
  return (unsigned char)(__builtin_amdgcn_cvt_pk_fp8_f32(f, f, 0, false) & 0xff);
}

__device__ __forceinline__ float waveRed(float v) {
#pragma unroll
  for (int m = 32; m >= 1; m >>= 1) v += __shfl_xor(v, m, 64);
  return v;
}

// async global->LDS, 16B per lane. LDS dest must be wave-uniform base + lane*16.
__device__ __forceinline__ void gload16(const void* g, void* l) {
  __builtin_amdgcn_global_load_lds(
      (__attribute__((address_space(1))) uint32_t*)(uintptr_t)g,
      (__attribute__((address_space(3))) uint32_t*)(uint32_t*)l,
      16, 0, 0);
}

// ---------------------------------------------------------------------------
// Small utility kernels
// ---------------------------------------------------------------------------
__global__ void zero_k(float* __restrict__ p, int n) {
  for (int i = blockIdx.x * 256 + threadIdx.x; i < n; i += gridDim.x * 256) p[i] = 0.f;
}

// x -> fp8 (e4m3) + sum of squares (fp32 exact path)
__global__ void cvtx8_k(const float4* __restrict__ x, uint32_t* __restrict__ x8,
                        float* __restrict__ sumsq, int n4) {
  float s = 0.f;
  for (int i = blockIdx.x * 256 + threadIdx.x; i < n4; i += gridDim.x * 256) {
    float4 v = x[i];
    int p = __builtin_amdgcn_cvt_pk_fp8_f32(v.x, v.y, 0, false);
    p = __builtin_amdgcn_cvt_pk_fp8_f32(v.z, v.w, p, true);
    x8[i] = (uint32_t)p;
    s += v.x * v.x + v.y * v.y + v.z * v.z + v.w * v.w;
  }
  s = waveRed(s);
  if ((threadIdx.x & 63) == 0) atomicAdd(sumsq, s);
}

__global__ void cvtw_k(const float4* __restrict__ in, ushort4* __restrict__ out, int n4) {
  for (int i = blockIdx.x * 256 + threadIdx.x; i < n4; i += gridDim.x * 256) {
    float4 v = in[i];
    ushort4 o;
    o.x = f2bf(v.x); o.y = f2bf(v.y); o.z = f2bf(v.z); o.w = f2bf(v.w);
    out[i] = o;
  }
}

__global__ void cvtw8_k(const float4* __restrict__ in, uint32_t* __restrict__ out, int n4) {
  for (int i = blockIdx.x * 256 + threadIdx.x; i < n4; i += gridDim.x * 256) {
    float4 v = in[i];
    int p = __builtin_amdgcn_cvt_pk_fp8_f32(v.x, v.y, 0, false);
    p = __builtin_amdgcn_cvt_pk_fp8_f32(v.z, v.w, p, true);
    out[i] = (uint32_t)p;
  }
}

// out[c*R + r] = f2bf(in[r*C + c]);  in: R x C fp32, out: C x R bf16
__global__ void trf_k(const float* __restrict__ in, unsigned short* __restrict__ out,
                      int R, int C, int n) {
  for (int o = blockIdx.x * 256 + threadIdx.x; o < n; o += gridDim.x * 256) {
    int c = o / R, r = o - c * R;
    out[o] = f2bf(in[(size_t)r * C + c]);
  }
}

// bf16 transpose: out[c*R + r] = in[r*C + c]
__global__ void trb_k(const unsigned short* __restrict__ in, unsigned short* __restrict__ out,
                      int R, int C, int n) {
  for (int o = blockIdx.x * 256 + threadIdx.x; o < n; o += gridDim.x * 256) {
    int c = o / R, r = o - c * R;
    out[o] = in[(size_t)r * C + c];
  }
}

// LDS-histogram label count
__global__ __launch_bounds__(256) void count_k(const int* __restrict__ lab,
                                               int* __restrict__ counts, int n) {
  __shared__ int h[512];
  for (int i = threadIdx.x; i < 512; i += 256) h[i] = 0;
  __syncthreads();
  for (int i = blockIdx.x * 256 + threadIdx.x; i < n; i += gridDim.x * 256)
    atomicAdd(&h[lab[i]], 1);
  __syncthreads();
  for (int i = threadIdx.x; i < 512; i += 256) {
    int v = h[i];
    if (v) atomicAdd(&counts[i], v);
  }
}

// single-wave shuffle scan
__global__ void prefix_k(const int* __restrict__ counts, int* __restrict__ offsets,
                         int* __restrict__ cursor, int nc) {
  const int lane = threadIdx.x;  // 64 threads
  int base = 0;
  for (int c0 = 0; c0 < nc; c0 += 64) {
    int v = counts[c0 + lane];
    int x = v;
#pragma unroll
    for (int d = 1; d < 64; d <<= 1) {
      int y = __shfl_up(x, d, 64);
      if (lane >= d) x += y;
    }
    int excl = base + x - v;
    offsets[c0 + lane] = excl;
    cursor[c0 + lane] = excl;
    base += __shfl(x, 63, 64);
  }
}

__global__ void scatter_k(const int* __restrict__ lab, int* __restrict__ cursor,
                          int* __restrict__ buckets, int n) {
  for (int i = blockIdx.x * 256 + threadIdx.x; i < n; i += gridDim.x * 256) {
    int pos = atomicAdd(&cursor[lab[i]], 1);
    buckets[pos] = i;
  }
}

// one block per class: sum rows (bucket list cached in LDS, 4x unrolled),
// then atomicAdd(||sums||^2 / count)
__global__ __launch_bounds__(256) void center_k(const float* __restrict__ x,
    const int* __restrict__ buckets, const int* __restrict__ offsets,
    const int* __restrict__ counts, float* __restrict__ out, int D) {
  const int c = blockIdx.x;
  const int cnt = counts[c];
  if (cnt == 0) return;
  const int beg = offsets[c];
  __shared__ int rs[512];
  const int d2 = threadIdx.x;            // D/2 == 256 threads
  float sx = 0.f, sy = 0.f;
  for (int base = 0; base < cnt; base += 512) {
    const int m = min(cnt - base, 512);
    __syncthreads();
    for (int i = threadIdx.x; i < m; i += 256) rs[i] = buckets[beg + base + i];
    __syncthreads();
    int r = 0;
    for (; r + 4 <= m; r += 4) {
      const float2 v0 = ((const float2*)(x + (size_t)rs[r + 0] * D))[d2];
      const float2 v1 = ((const float2*)(x + (size_t)rs[r + 1] * D))[d2];
      const float2 v2 = ((const float2*)(x + (size_t)rs[r + 2] * D))[d2];
      const float2 v3 = ((const float2*)(x + (size_t)rs[r + 3] * D))[d2];
      sx += v0.x + v1.x + v2.x + v3.x;
      sy += v0.y + v1.y + v2.y + v3.y;
    }
    for (; r < m; ++r) {
      const float2 v = ((const float2*)(x + (size_t)rs[r] * D))[d2];
      sx += v.x; sy += v.y;
    }
  }
  float ssq = sx * sx + sy * sy;
  ssq = waveRed(ssq);
  __shared__ float red[4];
  if ((threadIdx.x & 63) == 0) red[threadIdx.x >> 6] = ssq;
  __syncthreads();
  if (threadIdx.x == 0)
    atomicAdd(out, (red[0] + red[1] + red[2] + red[3]) / (float)cnt);
}

__global__ void copy_k(const float* __restrict__ in, float* __restrict__ out, int n) {
  for (int i = blockIdx.x * 256 + threadIdx.x; i < n; i += gridDim.x * 256) out[i] = in[i];
}

// vout[row] = badd[row] + sum_k W[row,K] vin[k]; one block per row
__global__ __launch_bounds__(256) void matvec_k(const float* __restrict__ W,
    const float* __restrict__ vin, const float* __restrict__ badd,
    float* __restrict__ vout, int K) {
  int row = blockIdx.x;
  float s = 0.f;
  for (int k = threadIdx.x; k < K; k += 256) s += W[(size_t)row * K + k] * vin[k];
  s = waveRed(s);
  __shared__ float red[4];
  if ((threadIdx.x & 63) == 0) red[threadIdx.x >> 6] = s;
  __syncthreads();
  if (threadIdx.x == 0) vout[row] = red[0] + red[1] + red[2] + red[3] + badd[row];
}

// ---------------------------------------------------------------------------
// bf16 MFMA GEMM (m97 structure) for the small weight-collapse products.
// C[M,N] = A[M,K] @ B[N,K]^T; writes bf16 (if Cb16) and/or fp8 (if C8).
// ---------------------------------------------------------------------------
#define BM 128
#define BN 128
#define BKK 32

__global__ __launch_bounds__(256) void gemm_bt(
    const unsigned short* __restrict__ A, const unsigned short* __restrict__ Bm,
    int M, int N, int K, unsigned short* __restrict__ Cb16,
    unsigned char* __restrict__ C8) {
  __shared__ __align__(16) unsigned short As[BM * BKK];
  __shared__ __align__(16) unsigned short Bs[BN * BKK];
  const int tid = threadIdx.x;
  const int lane = tid & 63;
  const int wave = tid >> 6;
  const int lane16 = lane & 15;
  const int quad = lane >> 4;
  const int wm = (wave >> 1) * 64;
  const int wn = (wave & 1) * 64;
  const int m0 = blockIdx.y * BM;
  const int n0 = blockIdx.x * BN;

  f32x4 acc[4][4] = {};

  const int srow = tid >> 2;
  const int skof = (tid & 3) * 8;
  const unsigned short* Ab = A + (size_t)(m0 + srow) * K + skof;
  const unsigned short* Bb = Bm + (size_t)(n0 + srow) * K + skof;
  const size_t rstep = (size_t)64 * K;

  for (int kt = 0; kt < K; kt += BKK) {
    gload16(Ab + kt,         &As[tid * 8]);
    gload16(Ab + rstep + kt, &As[2048 + tid * 8]);
    gload16(Bb + kt,         &Bs[tid * 8]);
    gload16(Bb + rstep + kt, &Bs[2048 + tid * 8]);
    __syncthreads();
    bf16x8 af[4], bfv[4];
#pragma unroll
    for (int i = 0; i < 4; ++i)
      af[i] = *(const bf16x8*)&As[(wm + i * 16 + lane16) * BKK + quad * 8];
#pragma unroll
    for (int j = 0; j < 4; ++j)
      bfv[j] = *(const bf16x8*)&Bs[(wn + j * 16 + lane16) * BKK + quad * 8];
#pragma unroll
    for (int i = 0; i < 4; ++i)
#pragma unroll
      for (int j = 0; j < 4; ++j)
        acc[i][j] = __builtin_amdgcn_mfma_f32_16x16x32_bf16(af[i], bfv[j], acc[i][j], 0, 0, 0);
    __syncthreads();
  }
#pragma unroll
  for (int i = 0; i < 4; ++i)
#pragma unroll
    for (int r = 0; r < 4; ++r) {
      const int rowg = m0 + wm + i * 16 + quad * 4 + r;
#pragma unroll
      for (int j = 0; j < 4; ++j) {
        const int colg = n0 + wn + j * 16 + lane16;
        const float v = acc[i][j][r];
        if (Cb16) Cb16[(size_t)rowg * N + colg] = f2bf(v);
        if (C8)   C8[(size_t)rowg * N + colg] = f2fp8(v);
      }
    }
}

// ---------------------------------------------------------------------------
// MX-fp8 fused logits+CE GEMM (m97/m148 structure).
// C = A[M,512] @ B[N,512]^T via mfma_scale_f32_16x16x128_f8f6f4, scales = 1.0.
// 128x128 tile, BK=128 (4 k-iters), LDS 2x16KB, global_load_lds staging with
// 32B super-chunk XOR swizzle (sc ^ (row&3)) to break the 128B-row-stride
// 16-way LDS bank conflict on fragment reads (-> 2-way aliasing = free).
// Epilogue: fused CE (bias add, expsum/picked atomics); logits not stored.
// ---------------------------------------------------------------------------
__global__ __launch_bounds__(256) void gemm_ce8(
    const unsigned char* __restrict__ A8, const unsigned char* __restrict__ B8,
    const float* __restrict__ bias, const int* __restrict__ labels,
    float* __restrict__ expsum, float* __restrict__ picked,
    int K, int Bsz, int lvl0n, int lvl1n) {
  __shared__ __align__(16) unsigned char As[128 * 128];
  __shared__ __align__(16) unsigned char Bs[128 * 128];
  const int tid = threadIdx.x;
  const int lane = tid & 63;
  const int wave = tid >> 6;
  const int lane16 = lane & 15;
  const int quad = lane >> 4;
  const int wm = (wave >> 1) * 64;
  const int wn = (wave & 1) * 64;
  const int m0 = blockIdx.y * 128;
  const int n0 = blockIdx.x * 128;

  f32x4 acc[4][4] = {};

  // staging slot s (0..1023): row = s>>3, 16B-chunk c16 = s&7;
  // fetch global 32B super-chunk ((c16>>1) ^ (row&3)), half (c16&1).
  int srow[4], goff[4];
#pragma unroll
  for (int q = 0; q < 4; ++q) {
    const int s = tid + q * 256;
    const int row = s >> 3;
    const int c16 = s & 7;
    srow[q] = row;
    goff[q] = (((c16 >> 1) ^ (row & 3)) << 5) + ((c16 & 1) << 4);
  }

  for (int kt = 0; kt < K; kt += 128) {
#pragma unroll
    for (int q = 0; q < 4; ++q) {
      const int s = tid + q * 256;
      gload16(A8 + (size_t)(m0 + srow[q]) * K + kt + goff[q], &As[s * 16]);
      gload16(B8 + (size_t)(n0 + srow[q]) * K + kt + goff[q], &Bs[s * 16]);
    }
    __syncthreads();
    i32x8v a8[4], b8[4];
#pragma unroll
    for (int i = 0; i < 4; ++i) {
      const int row = i * 16 + lane16;
      const int sc = quad ^ (row & 3);
      const unsigned char* pa = &As[row * 128 + sc * 32];
      const i32x4v lo = *(const i32x4v*)pa;
      const i32x4v hi = *(const i32x4v*)(pa + 16);
      a8[i] = (i32x8v){lo[0], lo[1], lo[2], lo[3], hi[0], hi[1], hi[2], hi[3]};
    }
#pragma unroll
    for (int j = 0; j < 4; ++j) {
      const int row = j * 16 + lane16;
      const int sc = quad ^ (row & 3);
      const unsigned char* pb = &Bs[row * 128 + sc * 32];
      const i32x4v lo = *(const i32x4v*)pb;
      const i32x4v hi = *(const i32x4v*)(pb + 16);
      b8[j] = (i32x8v){lo[0], lo[1], lo[2], lo[3], hi[0], hi[1], hi[2], hi[3]};
    }
#pragma unroll
    for (int i = 0; i < 4; ++i)
#pragma unroll
      for (int j = 0; j < 4; ++j)
        acc[i][j] = __builtin_amdgcn_mfma_scale_f32_16x16x128_f8f6f4(
            a8[i], b8[j], acc[i][j], 0, 0, 0, 0x7f7f7f7f, 0, 0x7f7f7f7f);
    __syncthreads();
  }

  // ---- fused CE epilogue (level boundaries are 128-aligned) ----
  int lvl, cbase;
  if (n0 < lvl0n)              { lvl = 0; cbase = 0; }
  else if (n0 < lvl0n + lvl1n) { lvl = 1; cbase = lvl0n; }
  else                         { lvl = 2; cbase = lvl0n + lvl1n; }
  float bj[4];
#pragma unroll
  for (int j = 0; j < 4; ++j) bj[j] = bias[n0 + wn + j * 16 + lane16];
  float* es = expsum + (size_t)lvl * Bsz;
  float* pk = picked + (size_t)lvl * Bsz;
#pragma unroll
  for (int i = 0; i < 4; ++i) {
#pragma unroll
    for (int r = 0; r < 4; ++r) {
      const int rowg = m0 + wm + i * 16 + quad * 4 + r;
      const int lab = labels[rowg];
      float part = 0.f;
#pragma unroll
      for (int j = 0; j < 4; ++j) {
        const float v = acc[i][j][r] + bj[j];
        part += __expf(v);
        if (n0 + wn + j * 16 + lane16 - cbase == lab) atomicAdd(&pk[rowg], v);
      }
      part += __shfl_xor(part, 1, 64);
      part += __shfl_xor(part, 2, 64);
      part += __shfl_xor(part, 4, 64);
      part += __shfl_xor(part, 8, 64);
      if (lane16 == 0) atomicAdd(&es[rowg], part);
    }
  }
}

// per-row nll over 3 levels, accumulate sums into nll[0..2]
__global__ void nll_k(const float* __restrict__ es, const float* __restrict__ pk,
                      float* __restrict__ nll, int B) {
  float l0 = 0.f, l1 = 0.f, l2 = 0.f;
  for (int i = blockIdx.x * 256 + threadIdx.x; i < B; i += gridDim.x * 256) {
    l0 += __logf(es[i])         - pk[i];
    l1 += __logf(es[i + B])     - pk[i + B];
    l2 += __logf(es[i + 2 * B]) - pk[i + 2 * B];
  }
  l0 = waveRed(l0); l1 = waveRed(l1); l2 = waveRed(l2);
  if ((threadIdx.x & 63) == 0) {
    atomicAdd(&nll[0], l0);
    atomicAdd(&nll[1], l1);
    atomicAdd(&nll[2], l2);
  }
}

// scal: [0]=sumsq_x [1]=sum ||sums_c||^2/n_c  [2..4]=nll sums
__global__ void fin_k(const float* __restrict__ scal, const float* __restrict__ lam,
                      float* __restrict__ out, float invB) {
  if (threadIdx.x == 0 && blockIdx.x == 0)
    out[0] = lam[0] * (scal[0] - scal[1]) +
             (lam[1] * scal[2] + lam[2] * scal[3] + lam[3] * scal[4]) * invB;
}

// ---------------------------------------------------------------------------
// Launch
// ---------------------------------------------------------------------------
extern "C" void kernel_launch(void* const* d_in, const int* in_sizes, int n_in,
                              void* d_out, int out_size, void* d_ws, size_t ws_size,
                              hipStream_t stream) {
  const float* x   = (const float*)d_in[0];
  const float* W0  = (const float*)d_in[1];
  const float* b0  = (const float*)d_in[2];
  const float* W1  = (const float*)d_in[3];
  const float* b1  = (const float*)d_in[4];
  const float* W2  = (const float*)d_in[5];
  const float* b2  = (const float*)d_in[6];
  const float* lam = (const float*)d_in[7];
  const int*   lab = (const int*)d_in[8];

  const int Bsz = in_sizes[8];         // 65536
  const int D   = in_sizes[0] / Bsz;   // 512
  const int N0  = in_sizes[2];         // 2048
  const int N1  = in_sizes[4];         // 1024
  const int N2  = in_sizes[6];         // 512
  const int Ncat = N0 + N1 + N2;       // 3584
  const int NCLS = 512;

  char* w = (char*)d_ws;
  size_t off = 0;
  auto alloc = [&](size_t bytes) -> void* {
    void* p = w + off;
    off += (bytes + 255) & ~(size_t)255;
    return p;
  };

  unsigned char* x8    = (unsigned char*)alloc((size_t)Bsz * D);
  unsigned char* Bcat8 = (unsigned char*)alloc((size_t)Ncat * D);
  unsigned short* W0t  = (unsigned short*)alloc((size_t)D * N0 * 2);
  unsigned short* W1b  = (unsigned short*)alloc((size_t)N1 * N0 * 2);
  unsigned short* W2b  = (unsigned short*)alloc((size_t)N2 * N1 * 2);
  unsigned short* M1   = (unsigned short*)alloc((size_t)N1 * D * 2);
  unsigned short* M1t  = (unsigned short*)alloc((size_t)D * N1 * 2);
  float* biascat = (float*)alloc((size_t)Ncat * 4);
  int* offsets = (int*)alloc(NCLS * 4);
  int* cursor  = (int*)alloc(NCLS * 4);
  int* buckets = (int*)alloc((size_t)Bsz * 4);
  // zero region: counts(512 int) | scal(8 float) | expsum(3*Bsz) | picked(3*Bsz)
  size_t zbytes = (size_t)NCLS * 4 + 32 + (size_t)3 * Bsz * 4 * 2;
  char* zr = (char*)alloc(zbytes);
  int*   counts = (int*)zr;
  float* scal   = (float*)(zr + NCLS * 4);
  float* expsum = (float*)(zr + NCLS * 4 + 32);
  float* picked = expsum + (size_t)3 * Bsz;
  (void)ws_size; (void)n_in; (void)out_size;

  const int zwords = (int)(zbytes / 4);
  zero_k<<<dim3((zwords + 255) / 256), dim3(256), 0, stream>>>((float*)zr, zwords);

  // x -> fp8 + sum of squares
  const int n4x = Bsz * D / 4;
  cvtx8_k<<<dim3(1024), dim3(256), 0, stream>>>((const float4*)x, (uint32_t*)x8, &scal[0], n4x);

  // weight conversions
  cvtw_k<<<dim3((N1 * N0 / 4 + 255) / 256), dim3(256), 0, stream>>>((const float4*)W1, (ushort4*)W1b, N1 * N0 / 4);
  cvtw_k<<<dim3((N2 * N1 / 4 + 255) / 256), dim3(256), 0, stream>>>((const float4*)W2, (ushort4*)W2b, N2 * N1 / 4);
  trf_k<<<dim3(4096), dim3(256), 0, stream>>>(W0, W0t, N0, D, N0 * D);
  cvtw8_k<<<dim3((N0 * D / 4 + 255) / 256), dim3(256), 0, stream>>>((const float4*)W0, (uint32_t*)Bcat8, N0 * D / 4);

  // center-loss bucketing
  count_k<<<dim3(32), dim3(256), 0, stream>>>(lab, counts, Bsz);
  prefix_k<<<dim3(1), dim3(64), 0, stream>>>(counts, offsets, cursor, NCLS);
  scatter_k<<<dim3(256), dim3(256), 0, stream>>>(lab, cursor, buckets, Bsz);
  center_k<<<dim3(NCLS), dim3(256), 0, stream>>>(x, buckets, offsets, counts, &scal[1], D);

  // collapsed biases: biascat = [b0 | b1 + W1 b0 | b2 + W2 c1]
  copy_k<<<dim3(8), dim3(256), 0, stream>>>(b0, biascat, N0);
  matvec_k<<<dim3(N1), dim3(256), 0, stream>>>(W1, b0, b1, biascat + N0, N0);
  matvec_k<<<dim3(N2), dim3(256), 0, stream>>>(W2, biascat + N0, b2, biascat + N0 + N1, N1);

  // collapsed weights: M1 = W1@W0 (N1 x D) -> bf16 scratch + fp8 into Bcat8
  gemm_bt<<<dim3(D / BN, N1 / BM), dim3(256), 0, stream>>>(
      W1b, W0t, N1, D, N0, M1, Bcat8 + (size_t)N0 * D);
  trb_k<<<dim3(2048), dim3(256), 0, stream>>>(M1, M1t, N1, D, N1 * D);
  // M2 = W2@M1 (N2 x D) -> fp8 into Bcat8 only
  gemm_bt<<<dim3(D / BN, N2 / BM), dim3(256), 0, stream>>>(
      W2b, M1t, N2, D, N1, nullptr, Bcat8 + (size_t)(N0 + N1) * D);

  // fused logits + CE, all three levels (MX-fp8)
  gemm_ce8<<<dim3(Ncat / 128, Bsz / 128), dim3(256), 0, stream>>>(
      x8, Bcat8, biascat, lab, expsum, picked, D, Bsz, N0, N1);

  // reduce nll and finalize
  nll_k<<<dim3(256), dim3(256), 0, stream>>>(expsum, picked, &scal[2], Bsz);
  fin_k<<<dim3(1), dim3(64), 0, stream>>>(scal, lam, (float*)d_out, 1.f / (float)Bsz);
}

// Round 4
// 719.543 us; speedup vs baseline: 1.9629x; 1.0614x over previous
//
#include <hip/hip_runtime.h>
#include <cstdint>
#include <cstddef>

// ---------------------------------------------------------------------------
// Types / helpers
// ---------------------------------------------------------------------------
using f32x4  = __attribute__((ext_vector_type(4))) float;
using i32x4v = __attribute__((ext_vector_type(4))) int;
using i32x8v = __attribute__((ext_vector_type(8))) int;

__device__ __forceinline__ unsigned char f2fp8(float f) {
  return (unsigned char)(__builtin_amdgcn_cvt_pk_fp8_f32(f, f, 0, false) & 0xff);
}

__device__ __forceinline__ float waveRed(float v) {
#pragma unroll
  for (int m = 32; m >= 1; m >>= 1) v += __shfl_xor(v, m, 64);
  return v;
}

// async global->LDS, 16B per lane. LDS dest must be wave-uniform base + lane*16.
__device__ __forceinline__ void gload16(const void* g, void* l) {
  __builtin_amdgcn_global_load_lds(
      (__attribute__((address_space(1))) uint32_t*)(uintptr_t)g,
      (__attribute__((address_space(3))) uint32_t*)(uint32_t*)l,
      16, 0, 0);
}

// ---------------------------------------------------------------------------
// Small utility kernels
// ---------------------------------------------------------------------------
__global__ void zero_k(float* __restrict__ p, int n) {
  for (int i = blockIdx.x * 256 + threadIdx.x; i < n; i += gridDim.x * 256) p[i] = 0.f;
}

// x -> fp8 (e4m3) + sum of squares (fp32 exact path)
__global__ void cvtx8_k(const float4* __restrict__ x, uint32_t* __restrict__ x8,
                        float* __restrict__ sumsq, int n4) {
  float s = 0.f;
  for (int i = blockIdx.x * 256 + threadIdx.x; i < n4; i += gridDim.x * 256) {
    float4 v = x[i];
    int p = __builtin_amdgcn_cvt_pk_fp8_f32(v.x, v.y, 0, false);
    p = __builtin_amdgcn_cvt_pk_fp8_f32(v.z, v.w, p, true);
    x8[i] = (uint32_t)p;
    s += v.x * v.x + v.y * v.y + v.z * v.z + v.w * v.w;
  }
  s = waveRed(s);
  if ((threadIdx.x & 63) == 0) atomicAdd(sumsq, s);
}

// fused weight prep: W1->fp8, W2->fp8, W0->fp8 (row-major), W0->fp8 transposed
// (LDS-tiled). Block ranges: [0,1024) W1, [1024,1280) W2, [1280,1536) W0,
// [1536,1792) W0^T 64x64 tiles.
__global__ __launch_bounds__(256) void prep_w(
    const float4* __restrict__ W1, const float4* __restrict__ W2,
    const float4* __restrict__ W0f4, const float* __restrict__ W0,
    uint32_t* __restrict__ W1_8, uint32_t* __restrict__ W2_8,
    uint32_t* __restrict__ W0_8, unsigned char* __restrict__ W0t8) {
  __shared__ unsigned char t8[64][65];
  const int b = blockIdx.x;
  const int tid = threadIdx.x;
  if (b < 1024) {
    for (int i = b * 256 + tid; i < 524288; i += 1024 * 256) {
      float4 v = W1[i];
      int p = __builtin_amdgcn_cvt_pk_fp8_f32(v.x, v.y, 0, false);
      p = __builtin_amdgcn_cvt_pk_fp8_f32(v.z, v.w, p, true);
      W1_8[i] = (uint32_t)p;
    }
  } else if (b < 1280) {
    for (int i = (b - 1024) * 256 + tid; i < 131072; i += 256 * 256) {
      float4 v = W2[i];
      int p = __builtin_amdgcn_cvt_pk_fp8_f32(v.x, v.y, 0, false);
      p = __builtin_amdgcn_cvt_pk_fp8_f32(v.z, v.w, p, true);
      W2_8[i] = (uint32_t)p;
    }
  } else if (b < 1536) {
    for (int i = (b - 1280) * 256 + tid; i < 262144; i += 256 * 256) {
      float4 v = W0f4[i];
      int p = __builtin_amdgcn_cvt_pk_fp8_f32(v.x, v.y, 0, false);
      p = __builtin_amdgcn_cvt_pk_fp8_f32(v.z, v.w, p, true);
      W0_8[i] = (uint32_t)p;
    }
  } else {
    // transpose W0 (2048 x 512 fp32) -> W0t8 (512 x 2048 fp8)
    const int t = b - 1536;             // 0..255 : 32 row-tiles x 8 col-tiles
    const int r0 = (t >> 3) * 64, c0 = (t & 7) * 64;
#pragma unroll
    for (int p = 0; p < 16; ++p) {
      const int row = p * 4 + (tid >> 6), col = tid & 63;
      t8[row][col] = f2fp8(W0[(size_t)(r0 + row) * 512 + c0 + col]);
    }
    __syncthreads();
#pragma unroll
    for (int p = 0; p < 16; ++p) {
      const int oc = p * 4 + (tid >> 6), orr = tid & 63;
      W0t8[(size_t)(c0 + oc) * 2048 + r0 + orr] = t8[orr][oc];
    }
  }
}

// LDS-histogram label count
__global__ __launch_bounds__(256) void count_k(const int* __restrict__ lab,
                                               int* __restrict__ counts, int n) {
  __shared__ int h[512];
  for (int i = threadIdx.x; i < 512; i += 256) h[i] = 0;
  __syncthreads();
  for (int i = blockIdx.x * 256 + threadIdx.x; i < n; i += gridDim.x * 256)
    atomicAdd(&h[lab[i]], 1);
  __syncthreads();
  for (int i = threadIdx.x; i < 512; i += 256) {
    int v = h[i];
    if (v) atomicAdd(&counts[i], v);
  }
}

// single-wave shuffle scan
__global__ void prefix_k(const int* __restrict__ counts, int* __restrict__ offsets,
                         int* __restrict__ cursor, int nc) {
  const int lane = threadIdx.x;  // 64 threads
  int base = 0;
  for (int c0 = 0; c0 < nc; c0 += 64) {
    int v = counts[c0 + lane];
    int x = v;
#pragma unroll
    for (int d = 1; d < 64; d <<= 1) {
      int y = __shfl_up(x, d, 64);
      if (lane >= d) x += y;
    }
    int excl = base + x - v;
    offsets[c0 + lane] = excl;
    cursor[c0 + lane] = excl;
    base += __shfl(x, 63, 64);
  }
}

__global__ void scatter_k(const int* __restrict__ lab, int* __restrict__ cursor,
                          int* __restrict__ buckets, int n) {
  for (int i = blockIdx.x * 256 + threadIdx.x; i < n; i += gridDim.x * 256) {
    int pos = atomicAdd(&cursor[lab[i]], 1);
    buckets[pos] = i;
  }
}

// per-class sums, 4 blocks per class (2048 blocks): each sums a quarter of the
// class's bucketed rows into centers[c][*] via atomics. fp32-exact path.
__global__ __launch_bounds__(256) void csum_k(const float* __restrict__ x,
    const int* __restrict__ buckets, const int* __restrict__ offsets,
    const int* __restrict__ counts, float* __restrict__ centers) {
  const int c = blockIdx.x >> 2, q = blockIdx.x & 3;
  const int cnt = counts[c];
  if (cnt == 0) return;
  const int beg = offsets[c];
  const int lo = beg + (cnt * q) / 4, hi = beg + (cnt * (q + 1)) / 4;
  const int t = threadIdx.x;
  float sx = 0.f, sy = 0.f;
  for (int i = lo; i < hi; ++i) {
    const int row = buckets[i];
    const float2 v = ((const float2*)(x + (size_t)row * 512))[t];
    sx += v.x; sy += v.y;
  }
  if (lo < hi) {
    atomicAdd(&centers[c * 512 + 2 * t], sx);
    atomicAdd(&centers[c * 512 + 2 * t + 1], sy);
  }
}

// ||centers[c]||^2 / n_c -> atomic add into out
__global__ __launch_bounds__(256) void cnorm_k(const float* __restrict__ centers,
    const int* __restrict__ counts, float* __restrict__ out) {
  const int c = blockIdx.x;
  const int cnt = counts[c];
  if (cnt == 0) return;
  const float2 v = ((const float2*)(centers + (size_t)c * 512))[threadIdx.x];
  float ssq = v.x * v.x + v.y * v.y;
  ssq = waveRed(ssq);
  __shared__ float red[4];
  if ((threadIdx.x & 63) == 0) red[threadIdx.x >> 6] = ssq;
  __syncthreads();
  if (threadIdx.x == 0)
    atomicAdd(out, (red[0] + red[1] + red[2] + red[3]) / (float)cnt);
}

__global__ void copy_k(const float* __restrict__ in, float* __restrict__ out, int n) {
  for (int i = blockIdx.x * 256 + threadIdx.x; i < n; i += gridDim.x * 256) out[i] = in[i];
}

// vout[row] = badd[row] + sum_k W[row,K] vin[k]; one block per row (fp32 exact)
__global__ __launch_bounds__(256) void matvec_k(const float* __restrict__ W,
    const float* __restrict__ vin, const float* __restrict__ badd,
    float* __restrict__ vout, int K) {
  int row = blockIdx.x;
  float s = 0.f;
  for (int k = threadIdx.x; k < K; k += 256) s += W[(size_t)row * K + k] * vin[k];
  s = waveRed(s);
  __shared__ float red[4];
  if ((threadIdx.x & 63) == 0) red[threadIdx.x >> 6] = s;
  __syncthreads();
  if (threadIdx.x == 0) vout[row] = red[0] + red[1] + red[2] + red[3] + badd[row];
}

// ---------------------------------------------------------------------------
// MX-fp8 GEMM for weight collapse: C[M,N] = A[M,K] @ B[N,K]^T, fp8 out
// (row-major C8, optional transposed Ct8). 128x128 tile, BK=128.
// ---------------------------------------------------------------------------
__global__ __launch_bounds__(256) void gemm8_w(
    const unsigned char* __restrict__ A8, const unsigned char* __restrict__ B8,
    int M, int N, int K, unsigned char* __restrict__ C8,
    unsigned char* __restrict__ Ct8) {
  __shared__ __align__(16) unsigned char As[128 * 128];
  __shared__ __align__(16) unsigned char Bs[128 * 128];
  const int tid = threadIdx.x;
  const int lane = tid & 63;
  const int wave = tid >> 6;
  const int lane16 = lane & 15;
  const int quad = lane >> 4;
  const int wm = (wave >> 1) * 64;
  const int wn = (wave & 1) * 64;
  const int m0 = blockIdx.y * 128;
  const int n0 = blockIdx.x * 128;

  f32x4 acc[4][4] = {};

  int srow[4], goff[4];
#pragma unroll
  for (int q = 0; q < 4; ++q) {
    const int s = tid + q * 256;
    const int row = s >> 3;
    const int c16 = s & 7;
    srow[q] = row;
    goff[q] = (((c16 >> 1) ^ (row & 3)) << 5) + ((c16 & 1) << 4);
  }

  for (int kt = 0; kt < K; kt += 128) {
#pragma unroll
    for (int q = 0; q < 4; ++q) {
      const int s = tid + q * 256;
      gload16(A8 + (size_t)(m0 + srow[q]) * K + kt + goff[q], &As[s * 16]);
      gload16(B8 + (size_t)(n0 + srow[q]) * K + kt + goff[q], &Bs[s * 16]);
    }
    __syncthreads();
    i32x8v a8[4], b8[4];
#pragma unroll
    for (int i = 0; i < 4; ++i) {
      const int row = i * 16 + lane16;
      const int sc = quad ^ (row & 3);
      const unsigned char* pa = &As[row * 128 + sc * 32];
      const i32x4v lo = *(const i32x4v*)pa;
      const i32x4v hi = *(const i32x4v*)(pa + 16);
      a8[i] = (i32x8v){lo[0], lo[1], lo[2], lo[3], hi[0], hi[1], hi[2], hi[3]};
    }
#pragma unroll
    for (int j = 0; j < 4; ++j) {
      const int row = j * 16 + lane16;
      const int sc = quad ^ (row & 3);
      const unsigned char* pb = &Bs[row * 128 + sc * 32];
      const i32x4v lo = *(const i32x4v*)pb;
      const i32x4v hi = *(const i32x4v*)(pb + 16);
      b8[j] = (i32x8v){lo[0], lo[1], lo[2], lo[3], hi[0], hi[1], hi[2], hi[3]};
    }
#pragma unroll
    for (int i = 0; i < 4; ++i)
#pragma unroll
      for (int j = 0; j < 4; ++j)
        acc[i][j] = __builtin_amdgcn_mfma_scale_f32_16x16x128_f8f6f4(
            a8[i], b8[j], acc[i][j], 0, 0, 0, 0x7f7f7f7f, 0, 0x7f7f7f7f);
    __syncthreads();
  }
#pragma unroll
  for (int i = 0; i < 4; ++i)
#pragma unroll
    for (int r = 0; r < 4; ++r) {
      const int rowg = m0 + wm + i * 16 + quad * 4 + r;
#pragma unroll
      for (int j = 0; j < 4; ++j) {
        const int colg = n0 + wn + j * 16 + lane16;
        const unsigned char v8 = f2fp8(acc[i][j][r]);
        C8[(size_t)rowg * N + colg] = v8;
        if (Ct8) Ct8[(size_t)colg * M + rowg] = v8;
      }
    }
}

// ---------------------------------------------------------------------------
// MX-fp8 fused logits+CE GEMM v2: 128x128 tile, BK=256 (2 k-iters, 4 barriers),
// LDS 2x32KB with 32B super-chunk XOR swizzle (sc ^ (row&7)).
// Epilogue: block-local LDS reduction of expsum/picked, then 128 coalesced
// global atomics per block.
// ---------------------------------------------------------------------------
__global__ __launch_bounds__(256) void gemm_ce8(
    const unsigned char* __restrict__ A8, const unsigned char* __restrict__ B8,
    const float* __restrict__ bias, const int* __restrict__ labels,
    float* __restrict__ expsum, float* __restrict__ picked,
    int K, int Bsz, int lvl0n, int lvl1n) {
  __shared__ __align__(16) unsigned char As[128 * 256];
  __shared__ __align__(16) unsigned char Bs[128 * 256];
  const int tid = threadIdx.x;
  const int lane = tid & 63;
  const int wave = tid >> 6;
  const int lane16 = lane & 15;
  const int quad = lane >> 4;
  const int wm = (wave >> 1) * 64;
  const int wn = (wave & 1) * 64;
  const int m0 = blockIdx.y * 128;
  const int n0 = blockIdx.x * 128;

  f32x4 acc[4][4] = {};

  // staging: tile = 128 rows x 256 k-bytes = 32KB = 2048 16B-slots, 8 rounds.
  // slot s: row = s>>4, c16 = s&15; global 32B super-chunk swizzled ^(row&7).
  int srow[8], goff[8];
#pragma unroll
  for (int q = 0; q < 8; ++q) {
    const int s = tid + q * 256;
    const int row = s >> 4;
    const int c16 = s & 15;
    srow[q] = row;
    goff[q] = (((c16 >> 1) ^ (row & 7)) << 5) + ((c16 & 1) << 4);
  }

  for (int kt = 0; kt < K; kt += 256) {
#pragma unroll
    for (int q = 0; q < 8; ++q) {
      const int s = tid + q * 256;
      gload16(A8 + (size_t)(m0 + srow[q]) * K + kt + goff[q], &As[s * 16]);
      gload16(B8 + (size_t)(n0 + srow[q]) * K + kt + goff[q], &Bs[s * 16]);
    }
    __syncthreads();
#pragma unroll
    for (int st = 0; st < 2; ++st) {
      i32x8v a8[4], b8[4];
#pragma unroll
      for (int i = 0; i < 4; ++i) {
        const int row = i * 16 + lane16;
        const int sc = (st * 4 + quad) ^ (row & 7);
        const unsigned char* pa = &As[row * 256 + sc * 32];
        const i32x4v lo = *(const i32x4v*)pa;
        const i32x4v hi = *(const i32x4v*)(pa + 16);
        a8[i] = (i32x8v){lo[0], lo[1], lo[2], lo[3], hi[0], hi[1], hi[2], hi[3]};
      }
#pragma unroll
      for (int j = 0; j < 4; ++j) {
        const int row = j * 16 + lane16;
        const int sc = (st * 4 + quad) ^ (row & 7);
        const unsigned char* pb = &Bs[row * 256 + sc * 32];
        const i32x4v lo = *(const i32x4v*)pb;
        const i32x4v hi = *(const i32x4v*)(pb + 16);
        b8[j] = (i32x8v){lo[0], lo[1], lo[2], lo[3], hi[0], hi[1], hi[2], hi[3]};
      }
#pragma unroll
      for (int i = 0; i < 4; ++i)
#pragma unroll
        for (int j = 0; j < 4; ++j)
          acc[i][j] = __builtin_amdgcn_mfma_scale_f32_16x16x128_f8f6f4(
              a8[i], b8[j], acc[i][j], 0, 0, 0, 0x7f7f7f7f, 0, 0x7f7f7f7f);
    }
    __syncthreads();
  }

  // ---- fused CE epilogue with block-level LDS reduction ----
  int lvl, cbase;
  if (n0 < lvl0n)              { lvl = 0; cbase = 0; }
  else if (n0 < lvl0n + lvl1n) { lvl = 1; cbase = lvl0n; }
  else                         { lvl = 2; cbase = lvl0n + lvl1n; }
  float bj[4];
  int colr[4];
#pragma unroll
  for (int j = 0; j < 4; ++j) {
    bj[j] = bias[n0 + wn + j * 16 + lane16];
    colr[j] = n0 + wn + j * 16 + lane16 - cbase;
  }
  float* shes = (float*)As;        // 128 floats (LDS dead after last barrier)
  float* shpk = shes + 128;        // 128 floats
  if (tid < 128) { shes[tid] = 0.f; shpk[tid] = 0.f; }
  __syncthreads();
#pragma unroll
  for (int i = 0; i < 4; ++i) {
#pragma unroll
    for (int r = 0; r < 4; ++r) {
      const int rl = wm + i * 16 + quad * 4 + r;
      const int lb = labels[m0 + rl];
      float part = 0.f;
#pragma unroll
      for (int j = 0; j < 4; ++j) {
        const float v = acc[i][j][r] + bj[j];
        part += __expf(v);
        if (colr[j] == lb) atomicAdd(&shpk[rl], v);
      }
      part += __shfl_xor(part, 1, 64);
      part += __shfl_xor(part, 2, 64);
      part += __shfl_xor(part, 4, 64);
      part += __shfl_xor(part, 8, 64);
      if (lane16 == 0) atomicAdd(&shes[rl], part);
    }
  }
  __syncthreads();
  if (tid < 128) {
    atomicAdd(&expsum[(size_t)lvl * Bsz + m0 + tid], shes[tid]);
    const float p = shpk[tid];
    if (p != 0.f) atomicAdd(&picked[(size_t)lvl * Bsz + m0 + tid], p);
  }
}

// per-row nll over 3 levels, accumulate sums into nll[0..2]
__global__ void nll_k(const float* __restrict__ es, const float* __restrict__ pk,
                      float* __restrict__ nll, int B) {
  float l0 = 0.f, l1 = 0.f, l2 = 0.f;
  for (int i = blockIdx.x * 256 + threadIdx.x; i < B; i += gridDim.x * 256) {
    l0 += __logf(es[i])         - pk[i];
    l1 += __logf(es[i + B])     - pk[i + B];
    l2 += __logf(es[i + 2 * B]) - pk[i + 2 * B];
  }
  l0 = waveRed(l0); l1 = waveRed(l1); l2 = waveRed(l2);
  if ((threadIdx.x & 63) == 0) {
    atomicAdd(&nll[0], l0);
    atomicAdd(&nll[1], l1);
    atomicAdd(&nll[2], l2);
  }
}

// scal: [0]=sumsq_x [1]=sum ||sums_c||^2/n_c  [2..4]=nll sums
__global__ void fin_k(const float* __restrict__ scal, const float* __restrict__ lam,
                      float* __restrict__ out, float invB) {
  if (threadIdx.x == 0 && blockIdx.x == 0)
    out[0] = lam[0] * (scal[0] - scal[1]) +
             (lam[1] * scal[2] + lam[2] * scal[3] + lam[3] * scal[4]) * invB;
}

// ---------------------------------------------------------------------------
// Launch
// ---------------------------------------------------------------------------
extern "C" void kernel_launch(void* const* d_in, const int* in_sizes, int n_in,
                              void* d_out, int out_size, void* d_ws, size_t ws_size,
                              hipStream_t stream) {
  const float* x   = (const float*)d_in[0];
  const float* W0  = (const float*)d_in[1];
  const float* b0  = (const float*)d_in[2];
  const float* W1  = (const float*)d_in[3];
  const float* b1  = (const float*)d_in[4];
  const float* W2  = (const float*)d_in[5];
  const float* b2  = (const float*)d_in[6];
  const float* lam = (const float*)d_in[7];
  const int*   lab = (const int*)d_in[8];

  const int Bsz = in_sizes[8];         // 65536
  const int D   = in_sizes[0] / Bsz;   // 512
  const int N0  = in_sizes[2];         // 2048
  const int N1  = in_sizes[4];         // 1024
  const int N2  = in_sizes[6];         // 512
  const int Ncat = N0 + N1 + N2;       // 3584
  const int NCLS = 512;

  char* w = (char*)d_ws;
  size_t off = 0;
  auto alloc = [&](size_t bytes) -> void* {
    void* p = w + off;
    off += (bytes + 255) & ~(size_t)255;
    return p;
  };

  unsigned char* x8    = (unsigned char*)alloc((size_t)Bsz * D);
  unsigned char* Bcat8 = (unsigned char*)alloc((size_t)Ncat * D);
  unsigned char* W1_8  = (unsigned char*)alloc((size_t)N1 * N0);
  unsigned char* W2_8  = (unsigned char*)alloc((size_t)N2 * N1);
  unsigned char* W0t8  = (unsigned char*)alloc((size_t)D * N0);
  unsigned char* M1t8  = (unsigned char*)alloc((size_t)D * N1);
  float* biascat = (float*)alloc((size_t)Ncat * 4);
  int* offsets = (int*)alloc(NCLS * 4);
  int* cursor  = (int*)alloc(NCLS * 4);
  int* buckets = (int*)alloc((size_t)Bsz * 4);
  // zero region: counts(512i) | scal(8f) | centers(512*512f) | es(3B) | pk(3B)
  size_t zbytes = (size_t)NCLS * 4 + 32 + (size_t)NCLS * 512 * 4 +
                  (size_t)3 * Bsz * 4 * 2;
  char* zr = (char*)alloc(zbytes);
  int*   counts  = (int*)zr;
  float* scal    = (float*)(zr + NCLS * 4);
  float* centers = (float*)(zr + NCLS * 4 + 32);
  float* expsum  = centers + (size_t)NCLS * 512;
  float* picked  = expsum + (size_t)3 * Bsz;
  (void)ws_size; (void)n_in; (void)out_size;

  const int zwords = (int)(zbytes / 4);
  zero_k<<<dim3((zwords + 255) / 256), dim3(256), 0, stream>>>((float*)zr, zwords);

  // x -> fp8 + sum of squares
  cvtx8_k<<<dim3(1024), dim3(256), 0, stream>>>((const float4*)x, (uint32_t*)x8,
                                                &scal[0], Bsz * D / 4);

  // fused weight prep (W1,W2,W0 -> fp8; W0^T -> fp8)
  prep_w<<<dim3(1792), dim3(256), 0, stream>>>(
      (const float4*)W1, (const float4*)W2, (const float4*)W0, W0,
      (uint32_t*)W1_8, (uint32_t*)W2_8, (uint32_t*)Bcat8, W0t8);

  // center-loss bucketing + class sums (fp32-exact)
  count_k<<<dim3(32), dim3(256), 0, stream>>>(lab, counts, Bsz);
  prefix_k<<<dim3(1), dim3(64), 0, stream>>>(counts, offsets, cursor, NCLS);
  scatter_k<<<dim3(256), dim3(256), 0, stream>>>(lab, cursor, buckets, Bsz);
  csum_k<<<dim3(4 * NCLS), dim3(256), 0, stream>>>(x, buckets, offsets, counts, centers);
  cnorm_k<<<dim3(NCLS), dim3(256), 0, stream>>>(centers, counts, &scal[1]);

  // collapsed biases: biascat = [b0 | b1 + W1 b0 | b2 + W2 c1] (fp32 exact)
  copy_k<<<dim3(8), dim3(256), 0, stream>>>(b0, biascat, N0);
  matvec_k<<<dim3(N1), dim3(256), 0, stream>>>(W1, b0, b1, biascat + N0, N0);
  matvec_k<<<dim3(N2), dim3(256), 0, stream>>>(W2, biascat + N0, b2, biascat + N0 + N1, N1);

  // collapsed weights (fp8): M1 = W1@W0 -> Bcat8 seg1 + M1t8; M2 = W2@M1 -> seg2
  gemm8_w<<<dim3(D / 128, N1 / 128), dim3(256), 0, stream>>>(
      W1_8, W0t8, N1, D, N0, Bcat8 + (size_t)N0 * D, M1t8);
  gemm8_w<<<dim3(D / 128, N2 / 128), dim3(256), 0, stream>>>(
      W2_8, M1t8, N2, D, N1, Bcat8 + (size_t)(N0 + N1) * D, nullptr);

  // fused logits + CE, all three levels (MX-fp8, BK=256)
  gemm_ce8<<<dim3(Ncat / 128, Bsz / 128), dim3(256), 0, stream>>>(
      x8, Bcat8, biascat, lab, expsum, picked, D, Bsz, N0, N1);

  // reduce nll and finalize
  nll_k<<<dim3(256), dim3(256), 0, stream>>>(expsum, picked, &scal[2], Bsz);
  fin_k<<<dim3(1), dim3(64), 0, stream>>>(scal, lam, (float*)d_out, 1.f / (float)Bsz);
}

// Round 5
// 488.098 us; speedup vs baseline: 2.8937x; 1.4742x over previous
//
#include <hip/hip_runtime.h>
#include <cstdint>
#include <cstddef>

// ---------------------------------------------------------------------------
// Types / helpers
// ---------------------------------------------------------------------------
using f32x4  = __attribute__((ext_vector_type(4))) float;
using i32x4v = __attribute__((ext_vector_type(4))) int;
using i32x8v = __attribute__((ext_vector_type(8))) int;

__device__ __forceinline__ unsigned char f2fp8(float f) {
  return (unsigned char)(__builtin_amdgcn_cvt_pk_fp8_f32(f, f, 0, false) & 0xff);
}

__device__ __forceinline__ float waveRed(float v) {
#pragma unroll
  for (int m = 32; m >= 1; m >>= 1) v += __shfl_xor(v, m, 64);
  return v;
}

// async global->LDS, 16B per lane. LDS dest must be wave-uniform base + lane*16.
__device__ __forceinline__ void gload16(const void* g, void* l) {
  __builtin_amdgcn_global_load_lds(
      (__attribute__((address_space(1))) uint32_t*)(uintptr_t)g,
      (__attribute__((address_space(3))) uint32_t*)(uint32_t*)l,
      16, 0, 0);
}

// ---------------------------------------------------------------------------
// prep_w: fused weight prep + workspace zeroing + b0 copy.
// blocks [0,1024)    : W1 -> fp8
// blocks [1024,1280) : W2 -> fp8
// blocks [1280,1536) : W0 -> fp8 row-major (Bcat8 seg0)
// blocks [1536,1792) : W0^T -> fp8 (LDS-tiled)
// blocks [1792,2819) : zero zr region (zwords)
// blocks [2819,2827) : biascat[0..2047] = b0
// ---------------------------------------------------------------------------
__global__ __launch_bounds__(256) void prep_w(
    const float4* __restrict__ W1, const float4* __restrict__ W2,
    const float4* __restrict__ W0f4, const float* __restrict__ W0,
    const float* __restrict__ b0,
    uint32_t* __restrict__ W1_8, uint32_t* __restrict__ W2_8,
    uint32_t* __restrict__ W0_8, unsigned char* __restrict__ W0t8,
    float* __restrict__ zr, int zwords, float* __restrict__ biascat) {
  __shared__ unsigned char t8[64][65];
  const int b = blockIdx.x;
  const int tid = threadIdx.x;
  if (b < 1024) {
    for (int i = b * 256 + tid; i < 524288; i += 1024 * 256) {
      float4 v = W1[i];
      int p = __builtin_amdgcn_cvt_pk_fp8_f32(v.x, v.y, 0, false);
      p = __builtin_amdgcn_cvt_pk_fp8_f32(v.z, v.w, p, true);
      W1_8[i] = (uint32_t)p;
    }
  } else if (b < 1280) {
    for (int i = (b - 1024) * 256 + tid; i < 131072; i += 256 * 256) {
      float4 v = W2[i];
      int p = __builtin_amdgcn_cvt_pk_fp8_f32(v.x, v.y, 0, false);
      p = __builtin_amdgcn_cvt_pk_fp8_f32(v.z, v.w, p, true);
      W2_8[i] = (uint32_t)p;
    }
  } else if (b < 1536) {
    for (int i = (b - 1280) * 256 + tid; i < 262144; i += 256 * 256) {
      float4 v = W0f4[i];
      int p = __builtin_amdgcn_cvt_pk_fp8_f32(v.x, v.y, 0, false);
      p = __builtin_amdgcn_cvt_pk_fp8_f32(v.z, v.w, p, true);
      W0_8[i] = (uint32_t)p;
    }
  } else if (b < 1792) {
    // transpose W0 (2048 x 512 fp32) -> W0t8 (512 x 2048 fp8)
    const int t = b - 1536;             // 32 row-tiles x 8 col-tiles
    const int r0 = (t >> 3) * 64, c0 = (t & 7) * 64;
#pragma unroll
    for (int p = 0; p < 16; ++p) {
      const int row = p * 4 + (tid >> 6), col = tid & 63;
      t8[row][col] = f2fp8(W0[(size_t)(r0 + row) * 512 + c0 + col]);
    }
    __syncthreads();
#pragma unroll
    for (int p = 0; p < 16; ++p) {
      const int oc = p * 4 + (tid >> 6), orr = tid & 63;
      W0t8[(size_t)(c0 + oc) * 2048 + r0 + orr] = t8[orr][oc];
    }
  } else if (b < 2819) {
    const int i = (b - 1792) * 256 + tid;
    if (i < zwords) zr[i] = 0.f;
  } else {
    const int i = (b - 2819) * 256 + tid;
    if (i < 2048) biascat[i] = b0[i];
  }
}

// LDS-histogram label count
__global__ __launch_bounds__(256) void count_k(const int* __restrict__ lab,
                                               int* __restrict__ counts, int n) {
  __shared__ int h[512];
  for (int i = threadIdx.x; i < 512; i += 256) h[i] = 0;
  __syncthreads();
  for (int i = blockIdx.x * 256 + threadIdx.x; i < n; i += gridDim.x * 256)
    atomicAdd(&h[lab[i]], 1);
  __syncthreads();
  for (int i = threadIdx.x; i < 512; i += 256) {
    int v = h[i];
    if (v) atomicAdd(&counts[i], v);
  }
}

// single-wave shuffle scan
__global__ void prefix_k(const int* __restrict__ counts, int* __restrict__ offsets,
                         int* __restrict__ cursor, int nc) {
  const int lane = threadIdx.x;  // 64 threads
  int base = 0;
  for (int c0 = 0; c0 < nc; c0 += 64) {
    int v = counts[c0 + lane];
    int x = v;
#pragma unroll
    for (int d = 1; d < 64; d <<= 1) {
      int y = __shfl_up(x, d, 64);
      if (lane >= d) x += y;
    }
    int excl = base + x - v;
    offsets[c0 + lane] = excl;
    cursor[c0 + lane] = excl;
    base += __shfl(x, 63, 64);
  }
}

__global__ void scatter_k(const int* __restrict__ lab, int* __restrict__ cursor,
                          int* __restrict__ buckets, int n) {
  for (int i = blockIdx.x * 256 + threadIdx.x; i < n; i += gridDim.x * 256) {
    int pos = atomicAdd(&cursor[lab[i]], 1);
    buckets[pos] = i;
  }
}

// per-class sums, 4 blocks per class: atomicAdd partial sums into centers
__global__ __launch_bounds__(256) void csum_k(const float* __restrict__ x,
    const int* __restrict__ buckets, const int* __restrict__ offsets,
    const int* __restrict__ counts, float* __restrict__ centers) {
  const int c = blockIdx.x >> 2, q = blockIdx.x & 3;
  const int cnt = counts[c];
  if (cnt == 0) return;
  const int beg = offsets[c];
  const int lo = beg + (cnt * q) / 4, hi = beg + (cnt * (q + 1)) / 4;
  const int t = threadIdx.x;
  float sx = 0.f, sy = 0.f;
  for (int i = lo; i < hi; ++i) {
    const int row = buckets[i];
    const float2 v = ((const float2*)(x + (size_t)row * 512))[t];
    sx += v.x; sy += v.y;
  }
  if (lo < hi) {
    atomicAdd(&centers[c * 512 + 2 * t], sx);
    atomicAdd(&centers[c * 512 + 2 * t + 1], sy);
  }
}

// ||centers[c]||^2 / n_c -> atomic add into out
__global__ __launch_bounds__(256) void cnorm_k(const float* __restrict__ centers,
    const int* __restrict__ counts, float* __restrict__ out) {
  const int c = blockIdx.x;
  const int cnt = counts[c];
  if (cnt == 0) return;
  const float2 v = ((const float2*)(centers + (size_t)c * 512))[threadIdx.x];
  float ssq = v.x * v.x + v.y * v.y;
  ssq = waveRed(ssq);
  __shared__ float red[4];
  if ((threadIdx.x & 63) == 0) red[threadIdx.x >> 6] = ssq;
  __syncthreads();
  if (threadIdx.x == 0)
    atomicAdd(out, (red[0] + red[1] + red[2] + red[3]) / (float)cnt);
}

// vout[row] = badd[row] + sum_k W[row,K] vin[k]; one block per row (fp32 exact)
__global__ __launch_bounds__(256) void matvec_k(const float* __restrict__ W,
    const float* __restrict__ vin, const float* __restrict__ badd,
    float* __restrict__ vout, int K) {
  int row = blockIdx.x;
  float s = 0.f;
  for (int k = threadIdx.x; k < K; k += 256) s += W[(size_t)row * K + k] * vin[k];
  s = waveRed(s);
  __shared__ float red[4];
  if ((threadIdx.x & 63) == 0) red[threadIdx.x >> 6] = s;
  __syncthreads();
  if (threadIdx.x == 0) vout[row] = red[0] + red[1] + red[2] + red[3] + badd[row];
}

// ---------------------------------------------------------------------------
// MX-fp8 GEMM for weight collapse: C[M,N] = A[M,K] @ B[N,K]^T, fp8 out
// (row-major C8, optional transposed Ct8). 128x128 tile, BK=128.
// ---------------------------------------------------------------------------
__global__ __launch_bounds__(256) void gemm8_w(
    const unsigned char* __restrict__ A8, const unsigned char* __restrict__ B8,
    int M, int N, int K, unsigned char* __restrict__ C8,
    unsigned char* __restrict__ Ct8) {
  __shared__ __align__(16) unsigned char As[128 * 128];
  __shared__ __align__(16) unsigned char Bs[128 * 128];
  const int tid = threadIdx.x;
  const int lane = tid & 63;
  const int wave = tid >> 6;
  const int lane16 = lane & 15;
  const int quad = lane >> 4;
  const int wm = (wave >> 1) * 64;
  const int wn = (wave & 1) * 64;
  const int m0 = blockIdx.y * 128;
  const int n0 = blockIdx.x * 128;

  f32x4 acc[4][4] = {};

  int srow[4], goff[4];
#pragma unroll
  for (int q = 0; q < 4; ++q) {
    const int s = tid + q * 256;
    const int row = s >> 3;
    const int c16 = s & 7;
    srow[q] = row;
    goff[q] = (((c16 >> 1) ^ (row & 3)) << 5) + ((c16 & 1) << 4);
  }

  for (int kt = 0; kt < K; kt += 128) {
#pragma unroll
    for (int q = 0; q < 4; ++q) {
      const int s = tid + q * 256;
      gload16(A8 + (size_t)(m0 + srow[q]) * K + kt + goff[q], &As[s * 16]);
      gload16(B8 + (size_t)(n0 + srow[q]) * K + kt + goff[q], &Bs[s * 16]);
    }
    __syncthreads();
    i32x8v a8[4], b8[4];
#pragma unroll
    for (int i = 0; i < 4; ++i) {
      const int row = i * 16 + lane16;
      const int sc = quad ^ (row & 3);
      const unsigned char* pa = &As[row * 128 + sc * 32];
      const i32x4v lo = *(const i32x4v*)pa;
      const i32x4v hi = *(const i32x4v*)(pa + 16);
      a8[i] = (i32x8v){lo[0], lo[1], lo[2], lo[3], hi[0], hi[1], hi[2], hi[3]};
    }
#pragma unroll
    for (int j = 0; j < 4; ++j) {
      const int row = j * 16 + lane16;
      const int sc = quad ^ (row & 3);
      const unsigned char* pb = &Bs[row * 128 + sc * 32];
      const i32x4v lo = *(const i32x4v*)pb;
      const i32x4v hi = *(const i32x4v*)(pb + 16);
      b8[j] = (i32x8v){lo[0], lo[1], lo[2], lo[3], hi[0], hi[1], hi[2], hi[3]};
    }
#pragma unroll
    for (int i = 0; i < 4; ++i)
#pragma unroll
      for (int j = 0; j < 4; ++j)
        acc[i][j] = __builtin_amdgcn_mfma_scale_f32_16x16x128_f8f6f4(
            a8[i], b8[j], acc[i][j], 0, 0, 0, 0x7f7f7f7f, 0, 0x7f7f7f7f);
    __syncthreads();
  }
#pragma unroll
  for (int i = 0; i < 4; ++i)
#pragma unroll
    for (int r = 0; r < 4; ++r) {
      const int rowg = m0 + wm + i * 16 + quad * 4 + r;
#pragma unroll
      for (int j = 0; j < 4; ++j) {
        const int colg = n0 + wn + j * 16 + lane16;
        const unsigned char v8 = f2fp8(acc[i][j][r]);
        C8[(size_t)rowg * N + colg] = v8;
        if (Ct8) Ct8[(size_t)colg * M + rowg] = v8;
      }
    }
}

// ---------------------------------------------------------------------------
// reorder: Bcat8 row-major (3584 x 512) -> fragment-major Bp.
// Element (col,k) -> offset (col>>6)*32768 + (k>>7)*8192 + ((col>>4)&3)*2048
//                    + ((((k>>5)&3)*16) + (col&15))*32 + (k&31)
// One thread per 32B k-chunk. Per (tile64, kt): 8KB contiguous; the gemm's
// stream pointer advances linearly 8KB per k-step.
// ---------------------------------------------------------------------------
__global__ void reorder_k(const unsigned char* __restrict__ in,
                          unsigned char* __restrict__ out) {
  const int id = blockIdx.x * 256 + threadIdx.x;   // 57344 chunks
  const int col = id >> 4;
  const int k32 = id & 15;                         // k/32
  const int kt = k32 >> 2, quad = k32 & 3;
  const size_t src = (size_t)col * 512 + k32 * 32;
  const size_t dst = (size_t)(col >> 6) * 32768 + (size_t)kt * 8192 +
                     (size_t)((col >> 4) & 3) * 2048 +
                     (size_t)(quad * 16 + (col & 15)) * 32;
  const uint4 a = *(const uint4*)(in + src);
  const uint4 b = *(const uint4*)(in + src + 16);
  *(uint4*)(out + dst) = a;
  *(uint4*)(out + dst + 16) = b;
}

// ---------------------------------------------------------------------------
// Zero-barrier streaming fused logits+CE GEMM.
// Block = 256 threads = 4 independent waves; wave owns 64 rows of x.
// A (64x512 fp8) lives in 128 VGPRs, converted in-kernel from fp32 x (fused
// sumsq). B streamed linearly from fragment-major Bp (L1/L2-resident) with
// depth-1 register prefetch. No LDS, no __syncthreads, no vmcnt(0) drains.
// CE accumulators (es[16], pk) in registers; per-level wave-reduce + 1 atomic.
// ---------------------------------------------------------------------------
__global__ __launch_bounds__(256, 1) void gemm_ce8(
    const float* __restrict__ x, const unsigned char* __restrict__ Bp,
    const float* __restrict__ bias, const int* __restrict__ labels,
    float* __restrict__ scal) {
  const int tid = threadIdx.x;
  const int lane = tid & 63;
  const int wave = tid >> 6;
  const int lane16 = lane & 15;
  const int quad = lane >> 4;
  const int m0 = blockIdx.x * 256 + wave * 64;

  // ---- A: 64 rows x 512 fp8 in VGPRs, fused fp32->fp8 + sumsq ----
  i32x8v a[4][4];
  float ss = 0.f;
#pragma unroll
  for (int i = 0; i < 4; ++i) {
    const float* xr = x + (size_t)(m0 + i * 16 + lane16) * 512 + quad * 32;
#pragma unroll
    for (int kt = 0; kt < 4; ++kt) {
      const float4* p4 = (const float4*)(xr + kt * 128);
      int d[8];
#pragma unroll
      for (int p = 0; p < 8; ++p) {
        const float4 f = p4[p];
        ss += f.x * f.x + f.y * f.y + f.z * f.z + f.w * f.w;
        int w_ = __builtin_amdgcn_cvt_pk_fp8_f32(f.x, f.y, 0, false);
        w_ = __builtin_amdgcn_cvt_pk_fp8_f32(f.z, f.w, w_, true);
        d[p] = w_;
      }
      a[i][kt] = (i32x8v){d[0], d[1], d[2], d[3], d[4], d[5], d[6], d[7]};
    }
  }
  ss = waveRed(ss);
  if (lane == 0) atomicAdd(&scal[0], ss);

  int labr[16];
#pragma unroll
  for (int i = 0; i < 4; ++i)
#pragma unroll
    for (int r = 0; r < 4; ++r)
      labr[i * 4 + r] = labels[m0 + i * 16 + quad * 4 + r];

  // ---- B stream: linear, depth-1 prefetch ----
  const unsigned char* bp = Bp + lane * 32;
  i32x8v bc[4], bn[4];
#pragma unroll
  for (int j = 0; j < 4; ++j) bc[j] = *(const i32x8v*)(bp + j * 2048);
  bp += 8192;

  float es[16];
#pragma unroll
  for (int k = 0; k < 16; ++k) es[k] = 0.f;
  float pk = 0.f;

  int tile = 0;
#pragma unroll 1
  for (int lvl = 0; lvl < 3; ++lvl) {
    const int nt = (lvl == 0) ? 32 : (lvl == 1) ? 16 : 8;
    const int cbase = (lvl == 0) ? 0 : (lvl == 1) ? 2048 : 3072;
#pragma unroll 1
    for (int t = 0; t < nt; ++t, ++tile) {
      f32x4 acc[4][4] = {};
#pragma unroll
      for (int kt = 0; kt < 4; ++kt) {
#pragma unroll
        for (int j = 0; j < 4; ++j) bn[j] = *(const i32x8v*)(bp + j * 2048);
        bp += 8192;
#pragma unroll
        for (int i = 0; i < 4; ++i)
#pragma unroll
          for (int j = 0; j < 4; ++j)
            acc[i][j] = __builtin_amdgcn_mfma_scale_f32_16x16x128_f8f6f4(
                a[i][kt], bc[j], acc[i][j], 0, 0, 0, 0x7f7f7f7f, 0, 0x7f7f7f7f);
#pragma unroll
        for (int j = 0; j < 4; ++j) bc[j] = bn[j];
      }
      // ---- register CE epilogue ----
      float bj[4];
      int colr[4];
#pragma unroll
      for (int j = 0; j < 4; ++j) {
        const int cg = tile * 64 + j * 16 + lane16;
        bj[j] = bias[cg];
        colr[j] = cg - cbase;
      }
#pragma unroll
      for (int i = 0; i < 4; ++i)
#pragma unroll
        for (int r = 0; r < 4; ++r) {
          const int lb = labr[i * 4 + r];
          float e = 0.f;
#pragma unroll
          for (int j = 0; j < 4; ++j) {
            const float v = acc[i][j][r] + bj[j];
            e += __expf(v);
            if (colr[j] == lb) pk += v;
          }
          es[i * 4 + r] += e;
        }
    }
    // ---- level close: reduce es over lane16, log, accumulate nll ----
    float ls = 0.f;
#pragma unroll
    for (int k = 0; k < 16; ++k) {
      float tot = es[k];
      tot += __shfl_xor(tot, 1, 64);
      tot += __shfl_xor(tot, 2, 64);
      tot += __shfl_xor(tot, 4, 64);
      tot += __shfl_xor(tot, 8, 64);
      if (lane16 == 0) ls += __logf(tot);
      es[k] = 0.f;
    }
    ls = waveRed(ls);
    pk = waveRed(pk);
    if (lane == 0) atomicAdd(&scal[2 + lvl], ls - pk);
    pk = 0.f;
  }
}

// scal: [0]=sumsq_x [1]=sum ||sums_c||^2/n_c  [2..4]=nll sums
__global__ void fin_k(const float* __restrict__ scal, const float* __restrict__ lam,
                      float* __restrict__ out, float invB) {
  if (threadIdx.x == 0 && blockIdx.x == 0)
    out[0] = lam[0] * (scal[0] - scal[1]) +
             (lam[1] * scal[2] + lam[2] * scal[3] + lam[3] * scal[4]) * invB;
}

// ---------------------------------------------------------------------------
// Launch
// ---------------------------------------------------------------------------
extern "C" void kernel_launch(void* const* d_in, const int* in_sizes, int n_in,
                              void* d_out, int out_size, void* d_ws, size_t ws_size,
                              hipStream_t stream) {
  const float* x   = (const float*)d_in[0];
  const float* W0  = (const float*)d_in[1];
  const float* b0  = (const float*)d_in[2];
  const float* W1  = (const float*)d_in[3];
  const float* b1  = (const float*)d_in[4];
  const float* W2  = (const float*)d_in[5];
  const float* b2  = (const float*)d_in[6];
  const float* lam = (const float*)d_in[7];
  const int*   lab = (const int*)d_in[8];

  const int Bsz = in_sizes[8];         // 65536
  const int D   = in_sizes[0] / Bsz;   // 512
  const int N0  = in_sizes[2];         // 2048
  const int N1  = in_sizes[4];         // 1024
  const int N2  = in_sizes[6];         // 512
  const int Ncat = N0 + N1 + N2;       // 3584
  const int NCLS = 512;

  char* w = (char*)d_ws;
  size_t off = 0;
  auto alloc = [&](size_t bytes) -> void* {
    void* p = w + off;
    off += (bytes + 255) & ~(size_t)255;
    return p;
  };

  unsigned char* Bcat8 = (unsigned char*)alloc((size_t)Ncat * D);        // row-major
  unsigned char* Bp    = (unsigned char*)alloc((size_t)Ncat * D + 8192); // frag-major (+slack)
  unsigned char* W1_8  = (unsigned char*)alloc((size_t)N1 * N0);
  unsigned char* W2_8  = (unsigned char*)alloc((size_t)N2 * N1);
  unsigned char* W0t8  = (unsigned char*)alloc((size_t)D * N0);
  unsigned char* M1t8  = (unsigned char*)alloc((size_t)D * N1);
  float* biascat = (float*)alloc((size_t)Ncat * 4);
  int* offsets = (int*)alloc(NCLS * 4);
  int* cursor  = (int*)alloc(NCLS * 4);
  int* buckets = (int*)alloc((size_t)Bsz * 4);
  // zero region: counts(512i) | scal(8f) | centers(512*512f)
  const int zwords = NCLS + 8 + NCLS * 512;
  char* zr = (char*)alloc((size_t)zwords * 4);
  int*   counts  = (int*)zr;
  float* scal    = (float*)(zr + NCLS * 4);
  float* centers = (float*)(zr + NCLS * 4 + 32);
  (void)ws_size; (void)n_in; (void)out_size;

  // fused prep: weight fp8 conversions + W0^T + zero + b0 copy
  prep_w<<<dim3(2827), dim3(256), 0, stream>>>(
      (const float4*)W1, (const float4*)W2, (const float4*)W0, W0, b0,
      (uint32_t*)W1_8, (uint32_t*)W2_8, (uint32_t*)Bcat8, W0t8,
      (float*)zr, zwords, biascat);

  // center-loss bucketing + class sums (fp32-exact)
  count_k<<<dim3(32), dim3(256), 0, stream>>>(lab, counts, Bsz);
  prefix_k<<<dim3(1), dim3(64), 0, stream>>>(counts, offsets, cursor, NCLS);
  scatter_k<<<dim3(256), dim3(256), 0, stream>>>(lab, cursor, buckets, Bsz);
  csum_k<<<dim3(4 * NCLS), dim3(256), 0, stream>>>(x, buckets, offsets, counts, centers);
  cnorm_k<<<dim3(NCLS), dim3(256), 0, stream>>>(centers, counts, &scal[1]);

  // collapsed biases: biascat = [b0 | b1 + W1 b0 | b2 + W2 c1] (fp32 exact)
  matvec_k<<<dim3(N1), dim3(256), 0, stream>>>(W1, b0, b1, biascat + N0, N0);
  matvec_k<<<dim3(N2), dim3(256), 0, stream>>>(W2, biascat + N0, b2, biascat + N0 + N1, N1);

  // collapsed weights (fp8): M1 = W1@W0 -> Bcat8 seg1 + M1t8; M2 = W2@M1 -> seg2
  gemm8_w<<<dim3(D / 128, N1 / 128), dim3(256), 0, stream>>>(
      W1_8, W0t8, N1, D, N0, Bcat8 + (size_t)N0 * D, M1t8);
  gemm8_w<<<dim3(D / 128, N2 / 128), dim3(256), 0, stream>>>(
      W2_8, M1t8, N2, D, N1, Bcat8 + (size_t)(N0 + N1) * D, nullptr);

  // row-major -> fragment-major
  reorder_k<<<dim3(Ncat * D / 32 / 256), dim3(256), 0, stream>>>(Bcat8, Bp);

  // zero-barrier streaming fused logits+CE (all three levels)
  gemm_ce8<<<dim3(Bsz / 256), dim3(256), 0, stream>>>(x, Bp, biascat, lab, scal);

  fin_k<<<dim3(1), dim3(64), 0, stream>>>(scal, lam, (float*)d_out, 1.f / (float)Bsz);
}